// Round 1
// baseline (128.129 us; speedup 1.0000x reference)
//
#include <hip/hip_runtime.h>
#include <stdint.h>

// Log-sparse causal attention, B=4 L=2048 H=8 E=D=64, fp32 in/out.
// Allowed distances delta = q - j: {0..7, 9, 13, 21, 37, 69, 133, 261, 517, 1029}
//
// R5: 64 queries/block (512 threads), stage span q0-69 .. q0+63 (133 rows) of
// K and V in LDS (72.3 KB -> 2 blocks/CU, 16 waves/CU with launch_bounds(512,4)).
// Near set now includes delta=69 (13 deltas from LDS); far = {133,261,517,1029}
// with a block-uniform skip when the whole block is causally masked for that
// delta. Far-K loads issued before the barrier, far-V loads before the softmax,
// so their global latency hides under barrier/LDS/VALU work.
// Row padded to 68 floats (272 B, 16B-aligned; 2-way-max bank aliasing on b128).

static constexpr int Bn = 4, Ln = 2048, Hn = 8, En = 64;
static constexpr int QPB = 64;            // queries per block
static constexpr int NT  = 512;           // threads per block (8 waves)
static constexpr int NEAR_MAX = 69;       // deltas <= this are staged
static constexpr int SPAN = NEAR_MAX + QPB;   // 133 rows: q0-69 .. q0+63
static constexpr int PADF = 68;           // floats per LDS row
static constexpr int NNEAR = 13;
static constexpr int NFAR  = 4;
static constexpr int NDELTA = NNEAR + NFAR;

__global__ __launch_bounds__(NT, 4) void logsparse_attn_kernel(
    const float* __restrict__ Q,
    const float* __restrict__ K,
    const float* __restrict__ V,
    float* __restrict__ O)
{
    constexpr int nearD[NNEAR] = {0,1,2,3,4,5,6,7,9,13,21,37,69};
    constexpr int farD[NFAR]   = {133,261,517,1029};

    __shared__ float Ks[SPAN * PADF];
    __shared__ float Vs[SPAN * PADF];

    // 1024 blocks = 32 heads x 32 query-chunks; bh = blockIdx%32 keeps one
    // head's blocks on one XCD under round-robin dispatch (4 MB K+V / XCD = L2).
    const int bh = blockIdx.x & 31;
    const int l  = blockIdx.x >> 5;
    const int b  = bh >> 3;
    const int h  = bh & 7;
    const int q0 = l * QPB;

    const int tid = threadIdx.x;
    const size_t bhBase = ((size_t)b * Ln * Hn + (size_t)h) * (size_t)En;
    constexpr int ROWF = Hn * En;         // 512 floats between consecutive rows

    const int sub = tid & 7;              // 8 lanes per query, 8 dims each
    const int qq  = tid >> 3;             // query within block [0,64)
    const int q   = q0 + qq;
    const int dimOff = sub * 8;
    const size_t rowQ = bhBase + (size_t)q * ROWF + dimOff;

    // ---- issue Q load first (independent of everything) ----
    const float4 q0v = *(const float4*)(Q + rowQ);
    const float4 q1v = *(const float4*)(Q + rowQ + 4);

    // ---- cooperative staging: 133 rows x 16 float4-chunks, K and V fused ----
    for (int idx = tid; idx < SPAN * 16; idx += NT) {
        const int rid = idx >> 4;
        const int ch  = idx & 15;
        int g = q0 - NEAR_MAX + rid;
        if (g < 0) g = 0;                 // finite data; masked later via p=0
        const size_t srcOff = bhBase + (size_t)g * ROWF + ch * 4;
        const int dst = rid * PADF + ch * 4;
        *(float4*)(Ks + dst) = *(const float4*)(K + srcOff);
        *(float4*)(Vs + dst) = *(const float4*)(V + srcOff);
    }

    // ---- Q chunk (8 floats), fold scale = 1/sqrt(64) ----
    const float qf[8] = { q0v.x*0.125f, q0v.y*0.125f, q0v.z*0.125f, q0v.w*0.125f,
                          q1v.x*0.125f, q1v.y*0.125f, q1v.z*0.125f, q1v.w*0.125f };

    // ---- far-K loads issued BEFORE the barrier: latency hides under the
    // barrier wait + near-phase LDS reads. Block-uniform skip when the whole
    // block is causally masked for this delta. ----
    bool farOn[NFAR];
    float4 fk0[NFAR], fk1[NFAR];
    #pragma unroll
    for (int d = 0; d < NFAR; ++d) {
        const int del = farD[d];
        farOn[d] = (q0 + QPB - 1 >= del);           // uniform per block
        if (farOn[d]) {
            const int j  = q - del;
            const int jc = (j < 0) ? 0 : j;         // p==0 later when j<0
            const float* kp = K + bhBase + (size_t)jc * ROWF + dimOff;
            fk0[d] = *(const float4*)(kp);
            fk1[d] = *(const float4*)(kp + 4);
        }
    }

    __syncthreads();

    // ---- near dot products from LDS (13 deltas) ----
    float sc[NDELTA];
    #pragma unroll
    for (int d = 0; d < NNEAR; ++d) {
        const int del = nearD[d];
        const float* kp = Ks + (qq + NEAR_MAX - del) * PADF + dimOff;
        const float4 k0 = *(const float4*)(kp);
        const float4 k1 = *(const float4*)(kp + 4);
        float s = qf[0]*k0.x + qf[1]*k0.y + qf[2]*k0.z + qf[3]*k0.w
                + qf[4]*k1.x + qf[5]*k1.y + qf[6]*k1.z + qf[7]*k1.w;
        s += __shfl_xor(s, 1);
        s += __shfl_xor(s, 2);
        s += __shfl_xor(s, 4);
        sc[d] = (q - del < 0) ? -__builtin_inff() : s;
    }

    // ---- far dot products from registers (4 deltas) ----
    #pragma unroll
    for (int d = 0; d < NFAR; ++d) {
        const int del = farD[d];
        float s = -__builtin_inff();
        if (farOn[d]) {
            float t = qf[0]*fk0[d].x + qf[1]*fk0[d].y + qf[2]*fk0[d].z + qf[3]*fk0[d].w
                    + qf[4]*fk1[d].x + qf[5]*fk1[d].y + qf[6]*fk1[d].z + qf[7]*fk1[d].w;
            t += __shfl_xor(t, 1);
            t += __shfl_xor(t, 2);
            t += __shfl_xor(t, 4);
            s = (q - del < 0) ? -__builtin_inff() : t;
        }
        sc[NNEAR + d] = s;
    }

    // ---- far-V loads issued BEFORE softmax: latency hides under the exp/max
    // VALU work and the near-PV LDS phase. ----
    float4 fv0[NFAR], fv1[NFAR];
    #pragma unroll
    for (int d = 0; d < NFAR; ++d) {
        if (farOn[d]) {
            const int j  = q - farD[d];
            const int jc = (j < 0) ? 0 : j;
            const float* vp = V + bhBase + (size_t)jc * ROWF + dimOff;
            fv0[d] = *(const float4*)(vp);
            fv1[d] = *(const float4*)(vp + 4);
        }
    }

    // ---- softmax over 17 scores (delta=0 always valid -> finite max) ----
    float m = sc[0];
    #pragma unroll
    for (int d = 1; d < NDELTA; ++d) m = fmaxf(m, sc[d]);
    float p[NDELTA];
    float sum = 0.0f;
    #pragma unroll
    for (int d = 0; d < NDELTA; ++d) {
        p[d] = __expf(sc[d] - m);         // exp(-inf)=0 for masked
        sum += p[d];
    }
    const float inv = 1.0f / sum;

    // ---- weighted sum of V rows: near from LDS, then far from registers ----
    float acc[8] = {0,0,0,0,0,0,0,0};
    #pragma unroll
    for (int d = 0; d < NNEAR; ++d) {
        const int del = nearD[d];
        const float* vp = Vs + (qq + NEAR_MAX - del) * PADF + dimOff;
        const float4 v0 = *(const float4*)(vp);
        const float4 v1 = *(const float4*)(vp + 4);
        const float w = p[d];
        acc[0] = fmaf(w, v0.x, acc[0]);
        acc[1] = fmaf(w, v0.y, acc[1]);
        acc[2] = fmaf(w, v0.z, acc[2]);
        acc[3] = fmaf(w, v0.w, acc[3]);
        acc[4] = fmaf(w, v1.x, acc[4]);
        acc[5] = fmaf(w, v1.y, acc[5]);
        acc[6] = fmaf(w, v1.z, acc[6]);
        acc[7] = fmaf(w, v1.w, acc[7]);
    }
    #pragma unroll
    for (int d = 0; d < NFAR; ++d) {
        if (farOn[d]) {                   // uniform; p==0 covers j<0 lanes
            const float w = p[NNEAR + d];
            acc[0] = fmaf(w, fv0[d].x, acc[0]);
            acc[1] = fmaf(w, fv0[d].y, acc[1]);
            acc[2] = fmaf(w, fv0[d].z, acc[2]);
            acc[3] = fmaf(w, fv0[d].w, acc[3]);
            acc[4] = fmaf(w, fv1[d].x, acc[4]);
            acc[5] = fmaf(w, fv1[d].y, acc[5]);
            acc[6] = fmaf(w, fv1[d].z, acc[6]);
            acc[7] = fmaf(w, fv1[d].w, acc[7]);
        }
    }

    float4 o0, o1;
    o0.x = acc[0]*inv; o0.y = acc[1]*inv; o0.z = acc[2]*inv; o0.w = acc[3]*inv;
    o1.x = acc[4]*inv; o1.y = acc[5]*inv; o1.z = acc[6]*inv; o1.w = acc[7]*inv;
    *(float4*)(O + rowQ)     = o0;
    *(float4*)(O + rowQ + 4) = o1;
}

extern "C" void kernel_launch(void* const* d_in, const int* in_sizes, int n_in,
                              void* d_out, int out_size, void* d_ws, size_t ws_size,
                              hipStream_t stream) {
    const float* Q = (const float*)d_in[0];
    const float* K = (const float*)d_in[1];
    const float* V = (const float*)d_in[2];
    float* O = (float*)d_out;

    const int nblocks = Bn * Hn * (Ln / QPB);   // 1024 blocks, 64 queries each
    logsparse_attn_kernel<<<nblocks, NT, 0, stream>>>(Q, K, V, O);
}

// Round 2
// 100.554 us; speedup vs baseline: 1.2742x; 1.2742x over previous
//
#include <hip/hip_runtime.h>
#include <stdint.h>

// Log-sparse causal attention, B=4 L=2048 H=8 E=D=64, fp32 in/out.
// Allowed distances delta = q - j: {0..7, 9, 13, 21, 37, 69, 133, 261, 517, 1029}
//
// R6: 64 queries/block (512 threads), NEAR_MAX=37: stage K+V rows q0-37..q0+63
// (101 rows, 54.9 KB LDS -> 2 blocks/CU, 16 waves/CU). 12 near deltas from LDS,
// 5 far deltas {69,133,261,517,1029} loaded inline from global (coalesced
// 2KB/wave streams, L2/L3-resident) with a block-uniform skip when the whole
// block is causally dead for that delta. vs R5: NO register prefetch arrays and
// p[] folded into sc[] -- R5's fk/fv arrays + launch_bounds(512,4) forced
// VGPR=64 and spilled ~40 floats/thread to scratch (WRITE_SIZE 73MB vs 17MB
// output). Row padded to 68 floats (272 B, 16B-aligned for ds_read_b128;
// (4*row+8*sub) mod 32 spreads banks evenly -> balanced minimal-8-cycle b128).

static constexpr int Bn = 4, Ln = 2048, Hn = 8, En = 64;
static constexpr int QPB = 64;            // queries per block
static constexpr int NT  = 512;           // threads per block (8 waves)
static constexpr int NEAR_MAX = 37;       // deltas <= this are staged
static constexpr int SPAN = NEAR_MAX + QPB;   // 101 rows: q0-37 .. q0+63
static constexpr int PADF = 68;           // floats per LDS row
static constexpr int NNEAR = 12;
static constexpr int NFAR  = 5;
static constexpr int NDELTA = NNEAR + NFAR;

__global__ __launch_bounds__(NT) void logsparse_attn_kernel(
    const float* __restrict__ Q,
    const float* __restrict__ K,
    const float* __restrict__ V,
    float* __restrict__ O)
{
    constexpr int nearD[NNEAR] = {0,1,2,3,4,5,6,7,9,13,21,37};
    constexpr int farD[NFAR]   = {69,133,261,517,1029};

    __shared__ float Ks[SPAN * PADF];
    __shared__ float Vs[SPAN * PADF];

    // 1024 blocks = 32 heads x 32 query-chunks; bh = blockIdx%32 keeps each
    // XCD on 4 fixed (b,h) pairs under round-robin dispatch (~4MB K+V = L2).
    const int bh = blockIdx.x & 31;
    const int l  = blockIdx.x >> 5;
    const int b  = bh >> 3;
    const int h  = bh & 7;
    const int q0 = l * QPB;

    const int tid = threadIdx.x;
    const size_t bhBase = ((size_t)b * Ln * Hn + (size_t)h) * (size_t)En;
    constexpr int ROWF = Hn * En;         // 512 floats between consecutive rows

    const int sub = tid & 7;              // 8 lanes per query, 8 dims each
    const int qq  = tid >> 3;             // query within block [0,64)
    const int q   = q0 + qq;
    const int dimOff = sub * 8;
    const size_t rowQ = bhBase + (size_t)q * ROWF + dimOff;

    // ---- issue Q load first (independent of staging) ----
    const float4 q0v = *(const float4*)(Q + rowQ);
    const float4 q1v = *(const float4*)(Q + rowQ + 4);

    // ---- cooperative staging: 101 rows x 16 float4-chunks, K and V fused ----
    for (int idx = tid; idx < SPAN * 16; idx += NT) {
        const int rid = idx >> 4;
        const int ch  = idx & 15;
        int g = q0 - NEAR_MAX + rid;
        if (g < 0) g = 0;                 // finite data; masked later via p=0
        const size_t srcOff = bhBase + (size_t)g * ROWF + ch * 4;
        const int dst = rid * PADF + ch * 4;
        *(float4*)(Ks + dst) = *(const float4*)(K + srcOff);
        *(float4*)(Vs + dst) = *(const float4*)(V + srcOff);
    }

    // ---- Q chunk (8 floats), fold scale = 1/sqrt(64) ----
    const float qf[8] = { q0v.x*0.125f, q0v.y*0.125f, q0v.z*0.125f, q0v.w*0.125f,
                          q1v.x*0.125f, q1v.y*0.125f, q1v.z*0.125f, q1v.w*0.125f };

    __syncthreads();

    // ---- scores: 12 near (LDS) + 5 far (global, inline loads) ----
    float sc[NDELTA];
    #pragma unroll
    for (int d = 0; d < NNEAR; ++d) {
        const int del = nearD[d];
        const float* kp = Ks + (qq + NEAR_MAX - del) * PADF + dimOff;
        const float4 k0 = *(const float4*)(kp);
        const float4 k1 = *(const float4*)(kp + 4);
        float s = qf[0]*k0.x + qf[1]*k0.y + qf[2]*k0.z + qf[3]*k0.w
                + qf[4]*k1.x + qf[5]*k1.y + qf[6]*k1.z + qf[7]*k1.w;
        s += __shfl_xor(s, 1);
        s += __shfl_xor(s, 2);
        s += __shfl_xor(s, 4);
        sc[d] = (q - del < 0) ? -__builtin_inff() : s;
    }
    #pragma unroll
    for (int d = 0; d < NFAR; ++d) {
        const int del = farD[d];
        float s = -__builtin_inff();
        if (q0 + QPB - 1 >= del) {        // block-uniform: skip dead deltas
            const int j  = q - del;
            const int jc = (j < 0) ? 0 : j;   // p==0 later when j<0
            const float* kp = K + bhBase + (size_t)jc * ROWF + dimOff;
            const float4 k0 = *(const float4*)(kp);
            const float4 k1 = *(const float4*)(kp + 4);
            float t = qf[0]*k0.x + qf[1]*k0.y + qf[2]*k0.z + qf[3]*k0.w
                    + qf[4]*k1.x + qf[5]*k1.y + qf[6]*k1.z + qf[7]*k1.w;
            t += __shfl_xor(t, 1);
            t += __shfl_xor(t, 2);
            t += __shfl_xor(t, 4);
            s = (j < 0) ? -__builtin_inff() : t;
        }
        sc[NNEAR + d] = s;
    }

    // ---- softmax over 17 scores; p overwrites sc (register economy) ----
    float m = sc[0];
    #pragma unroll
    for (int d = 1; d < NDELTA; ++d) m = fmaxf(m, sc[d]);
    float sum = 0.0f;
    #pragma unroll
    for (int d = 0; d < NDELTA; ++d) {
        sc[d] = __expf(sc[d] - m);        // exp(-inf)=0 for masked
        sum += sc[d];
    }
    const float inv = 1.0f / sum;

    // ---- weighted sum of V rows: near from LDS, far from global inline ----
    float acc[8] = {0,0,0,0,0,0,0,0};
    #pragma unroll
    for (int d = 0; d < NNEAR; ++d) {
        const int del = nearD[d];
        const float* vp = Vs + (qq + NEAR_MAX - del) * PADF + dimOff;
        const float4 v0 = *(const float4*)(vp);
        const float4 v1 = *(const float4*)(vp + 4);
        const float w = sc[d];
        acc[0] = fmaf(w, v0.x, acc[0]);
        acc[1] = fmaf(w, v0.y, acc[1]);
        acc[2] = fmaf(w, v0.z, acc[2]);
        acc[3] = fmaf(w, v0.w, acc[3]);
        acc[4] = fmaf(w, v1.x, acc[4]);
        acc[5] = fmaf(w, v1.y, acc[5]);
        acc[6] = fmaf(w, v1.z, acc[6]);
        acc[7] = fmaf(w, v1.w, acc[7]);
    }
    #pragma unroll
    for (int d = 0; d < NFAR; ++d) {
        const int del = farD[d];
        if (q0 + QPB - 1 >= del) {        // uniform; p==0 covers j<0 lanes
            const int j  = q - del;
            const int jc = (j < 0) ? 0 : j;
            const float* vp = V + bhBase + (size_t)jc * ROWF + dimOff;
            const float4 v0 = *(const float4*)(vp);
            const float4 v1 = *(const float4*)(vp + 4);
            const float w = sc[NNEAR + d];
            acc[0] = fmaf(w, v0.x, acc[0]);
            acc[1] = fmaf(w, v0.y, acc[1]);
            acc[2] = fmaf(w, v0.z, acc[2]);
            acc[3] = fmaf(w, v0.w, acc[3]);
            acc[4] = fmaf(w, v1.x, acc[4]);
            acc[5] = fmaf(w, v1.y, acc[5]);
            acc[6] = fmaf(w, v1.z, acc[6]);
            acc[7] = fmaf(w, v1.w, acc[7]);
        }
    }

    float4 o0, o1;
    o0.x = acc[0]*inv; o0.y = acc[1]*inv; o0.z = acc[2]*inv; o0.w = acc[3]*inv;
    o1.x = acc[4]*inv; o1.y = acc[5]*inv; o1.z = acc[6]*inv; o1.w = acc[7]*inv;
    *(float4*)(O + rowQ)     = o0;
    *(float4*)(O + rowQ + 4) = o1;
}

extern "C" void kernel_launch(void* const* d_in, const int* in_sizes, int n_in,
                              void* d_out, int out_size, void* d_ws, size_t ws_size,
                              hipStream_t stream) {
    const float* Q = (const float*)d_in[0];
    const float* K = (const float*)d_in[1];
    const float* V = (const float*)d_in[2];
    float* O = (float*)d_out;

    const int nblocks = Bn * Hn * (Ln / QPB);   // 1024 blocks, 64 queries each
    logsparse_attn_kernel<<<nblocks, NT, 0, stream>>>(Q, K, V, O);
}